// Round 1
// baseline (266.156 us; speedup 1.0000x reference)
//
#include <hip/hip_runtime.h>
#include <hip/hip_bf16.h>
#include <math.h>

#define Bsz  8
#define Nseq 1024
#define Cdim 1024
#define Hh   16
#define Dd   64

typedef short short8 __attribute__((ext_vector_type(8)));
typedef float floatx4 __attribute__((ext_vector_type(4)));

__device__ __forceinline__ unsigned short f2bf(float f) {
    __hip_bfloat16 h = __float2bfloat16(f);
    return __builtin_bit_cast(unsigned short, h);
}

// async 16B global -> LDS. LDS dest is wave-uniform base + lane*16 (HW rule).
__device__ __forceinline__ void async16(const void* g, void* l) {
    __builtin_amdgcn_global_load_lds(
        (const __attribute__((address_space(1))) unsigned int*)g,
        (__attribute__((address_space(3))) unsigned int*)l, 16, 0, 0);
}

// pack two fp32 -> two bf16 (round-half-up) in one dword
__device__ __forceinline__ unsigned pack_bf16(float lo, float hi) {
    unsigned ulo = __float_as_uint(lo) + 0x8000u;
    unsigned uhi = __float_as_uint(hi) + 0x8000u;
    return __builtin_amdgcn_perm(uhi, ulo, 0x07060302);  // [ulo>>16, uhi>>16]
}

// ---------------------------------------------------------------------------
// PREP (fused): [0,8192) convert X fp32->bf16; [8192,8960) transpose w_qkv;
// [8960,9216) transpose w_proj; [9216,9344) RoPE table.
// ---------------------------------------------------------------------------
__global__ __launch_bounds__(256) void prep(
    const float* __restrict__ x, const float* __restrict__ w_qkv,
    const float* __restrict__ w_proj,
    unsigned short* __restrict__ xb, unsigned short* __restrict__ wqkvt,
    unsigned short* __restrict__ wprojt, float2* __restrict__ rope)
{
    __shared__ float T[64][65];
    const int blk = blockIdx.x;
    const int tid = threadIdx.x;

    if (blk < 8192) {
        int i = blk * 256 + tid;
        float4 v = ((const float4*)x)[i];
        ushort4 u;
        u.x = f2bf(v.x); u.y = f2bf(v.y); u.z = f2bf(v.z); u.w = f2bf(v.w);
        ((ushort4*)xb)[i] = u;
        return;
    }
    if (blk < 9216) {
        const float* in;
        unsigned short* out;
        int R = 1024, Ccols, c0, r0;
        if (blk < 8960) {
            int b2 = blk - 8192;
            in = w_qkv; out = wqkvt; Ccols = 3072;
            c0 = (b2 % 48) * 64; r0 = (b2 / 48) * 64;
        } else {
            int b2 = blk - 8960;
            in = w_proj; out = wprojt; Ccols = 1024;
            c0 = (b2 % 16) * 64; r0 = (b2 / 16) * 64;
        }
        for (int i = tid; i < 4096; i += 256) {
            int r = i >> 6, c = i & 63;
            T[r][c] = in[(size_t)(r0 + r) * Ccols + c0 + c];
        }
        __syncthreads();
        for (int i = tid; i < 4096; i += 256) {
            int rr = i >> 6, cc = i & 63;
            out[(size_t)(c0 + rr) * R + r0 + cc] = f2bf(T[cc][rr]);
        }
        return;
    }
    {
        int i = (blk - 9216) * 256 + tid;     // 0..32767
        int n = i >> 5, p = i & 31;
        float omega = __expf(-(float)p * 0.2878231366242557f);
        float sv, cv;
        sincosf((float)n * omega, &sv, &cv);
        rope[i] = make_float2(cv, sv);
    }
}

// ---------------------------------------------------------------------------
// 256x256 8-phase bf16 MFMA GEMM (T2+T3+T4+T5): BK=64, 8 waves (2M x 4N),
// 128 KiB LDS double buffer, counted vmcnt (6/8, never 0 in steady state),
// chunk-XOR LDS swizzle (chunk c of row r at slot c^(r&7); staged via
// pre-swizzled global source so LDS dest stays linear).
//
// Per-wave output = two 64-row stripes x two 32-col stripes (so the LDS
// A/B halves used per phase are CONTIGUOUS 128-row regions -> stageable):
//   rows: mh*128 + wm*64 + mi*16 ..    cols: nh*128 + wn*32 + ni*16 ..
// Phase p of tile T computes quadrant (mh,nh) = (0,0),(0,1),(1,0),(1,1).
// Staging per tile T: p1: A-half1(T+1)->buf[nxt]  p2: B-half1(T+1)->buf[nxt]
//                     p3: A-half0(T+2)->buf[cur]  p4: B-half0(T+2)->buf[cur]
// (A0/B0 of cur are last ds_read in phase 1 -> free after phase-2 barrier.)
// Waits: p1 vmcnt(6) guards A1(T),B1(T); p4 vmcnt(8) guards A0(T+1),B0(T+1).
//
// MODE 0: N=3072 QKV; epilogue RoPE-scatters q,k -> (B,H,N,D) and
//         LDS-transposes v -> vt (B,H,D,N).
// MODE 1: N=1024, +bias -> fp32 out.
// ---------------------------------------------------------------------------
__device__ __forceinline__ void load_a4(short8 ar[4][2], const short* buf,
                                        int rowbase, int ml, int quad) {
    #pragma unroll
    for (int mi = 0; mi < 4; ++mi)
        #pragma unroll
        for (int ks = 0; ks < 2; ++ks) {
            int sl = ((ks * 4 + quad) ^ (ml & 7)) * 8;
            ar[mi][ks] = *(const short8*)&buf[(rowbase + mi * 16 + ml) * 64 + sl];
        }
}
__device__ __forceinline__ void load_b2(short8 br[2][2], const short* buf,
                                        int rowbase, int ml, int quad) {
    #pragma unroll
    for (int ni = 0; ni < 2; ++ni)
        #pragma unroll
        for (int ks = 0; ks < 2; ++ks) {
            int sl = ((ks * 4 + quad) ^ (ml & 7)) * 8;
            br[ni][ks] = *(const short8*)&buf[(rowbase + ni * 16 + ml) * 64 + sl];
        }
}
__device__ __forceinline__ void mma16(floatx4 acc[4][2], const short8 ar[4][2],
                                      const short8 br[2][2]) {
    #pragma unroll
    for (int ks = 0; ks < 2; ++ks)
        #pragma unroll
        for (int mi = 0; mi < 4; ++mi)
            #pragma unroll
            for (int ni = 0; ni < 2; ++ni)
                acc[mi][ni] = __builtin_amdgcn_mfma_f32_16x16x32_bf16(
                    ar[mi][ks], br[ni][ks], acc[mi][ni], 0, 0, 0);
}
// stage one 128-row half (2 issue rounds; each: 8 waves x 8 rows x 16B)
__device__ __forceinline__ void stage_half(const unsigned short* g, short* dst,
                                           int half, int k0, int wave, int lr,
                                           int lchunk) {
    #pragma unroll
    for (int rr = 0; rr < 2; ++rr) {
        int row = half * 128 + rr * 64 + wave * 8;
        async16(g + (size_t)(row + lr) * 1024 + k0 + lchunk, dst + row * 64);
    }
}

#define GTILE(CUR, T, S12, S34, VM1, VM4S)                                   \
{                                                                            \
    /* P1: quadrant (0,0) */                                                 \
    load_a4(ar, Ab[CUR], wm * 64, ml, quad);                                 \
    load_b2(br[0], Bb[CUR], wn * 32, ml, quad);                              \
    if (S12) stage_half(Ag, Ab[1 - (CUR)], 1, ((T) + 1) * 64, wave, lr, lchunk); \
    asm volatile("s_waitcnt vmcnt(" #VM1 ")" ::: "memory");                  \
    __builtin_amdgcn_s_barrier();                                            \
    asm volatile("s_waitcnt lgkmcnt(0)" ::: "memory");                       \
    __builtin_amdgcn_s_setprio(1);                                           \
    mma16(acc[0][0], ar, br[0]);                                             \
    __builtin_amdgcn_s_setprio(0);                                           \
    __builtin_amdgcn_s_barrier();                                            \
    asm volatile("" ::: "memory");                                           \
    /* P2: quadrant (0,1) */                                                 \
    load_b2(br[1], Bb[CUR], 128 + wn * 32, ml, quad);                        \
    if (S12) stage_half(Bg, Bb[1 - (CUR)], 1, ((T) + 1) * 64, wave, lr, lchunk); \
    __builtin_amdgcn_s_barrier();                                            \
    asm volatile("s_waitcnt lgkmcnt(0)" ::: "memory");                       \
    __builtin_amdgcn_s_setprio(1);                                           \
    mma16(acc[0][1], ar, br[1]);                                             \
    __builtin_amdgcn_s_setprio(0);                                           \
    __builtin_amdgcn_s_barrier();                                            \
    asm volatile("" ::: "memory");                                           \
    /* P3: quadrant (1,0) */                                                 \
    load_a4(ar, Ab[CUR], 128 + wm * 64, ml, quad);                           \
    if (S34) stage_half(Ag, Ab[CUR], 0, ((T) + 2) * 64, wave, lr, lchunk);   \
    __builtin_amdgcn_s_barrier();                                            \
    asm volatile("s_waitcnt lgkmcnt(0)" ::: "memory");                       \
    __builtin_amdgcn_s_setprio(1);                                           \
    mma16(acc[1][0], ar, br[0]);                                             \
    __builtin_amdgcn_s_setprio(0);                                           \
    __builtin_amdgcn_s_barrier();                                            \
    asm volatile("" ::: "memory");                                           \
    /* P4: quadrant (1,1) — no ds_reads (frags live in regs) */              \
    if (S34) stage_half(Bg, Bb[CUR], 0, ((T) + 2) * 64, wave, lr, lchunk);   \
    VM4S;                                                                    \
    __builtin_amdgcn_s_barrier();                                            \
    __builtin_amdgcn_s_setprio(1);                                           \
    mma16(acc[1][1], ar, br[1]);                                             \
    __builtin_amdgcn_s_setprio(0);                                           \
    __builtin_amdgcn_s_barrier();                                            \
    asm volatile("" ::: "memory");                                           \
}
#define VMW(n) asm volatile("s_waitcnt vmcnt(" #n ")" ::: "memory")

template <int MODE>
__global__ __launch_bounds__(512, 2) void gemm256(
    const unsigned short* __restrict__ A, const unsigned short* __restrict__ Bt,
    const float* __restrict__ bias, const float2* __restrict__ rope,
    unsigned short* __restrict__ qb, unsigned short* __restrict__ kb,
    unsigned short* __restrict__ vtb, float* __restrict__ out)
{
    __shared__ __attribute__((aligned(16))) short SM[65536];   // 128 KiB
    const int tid  = threadIdx.x;
    const int wave = tid >> 6, lane = tid & 63;
    const int ml = lane & 15, quad = lane >> 4;
    const int lr     = lane >> 3;                 // row within 8-row group
    const int lchunk = ((lane & 7) ^ lr) * 8;     // swizzled source chunk
    const int wm = wave >> 2, wn = wave & 3;
    const int bm = blockIdx.y * 256, bn = blockIdx.x * 256;

    const unsigned short* Ag = A  + (size_t)bm * 1024;
    const unsigned short* Bg = Bt + (size_t)bn * 1024;
    short* const Ab[2] = { SM,         SM + 16384 };
    short* const Bb[2] = { SM + 32768, SM + 49152 };

    floatx4 acc[2][2][4][2] = {};   // [mh][nh][mi][ni]
    short8 ar[4][2], br[2][2][2];   // br[nh][ni][ks]

    // prologue: A0(0) B0(0) A1(0) B1(0) A0(1) B0(1); wait 4 oldest
    stage_half(Ag, Ab[0], 0,  0, wave, lr, lchunk);
    stage_half(Bg, Bb[0], 0,  0, wave, lr, lchunk);
    stage_half(Ag, Ab[0], 1,  0, wave, lr, lchunk);
    stage_half(Bg, Bb[0], 1,  0, wave, lr, lchunk);
    stage_half(Ag, Ab[1], 0, 64, wave, lr, lchunk);
    stage_half(Bg, Bb[1], 0, 64, wave, lr, lchunk);
    asm volatile("s_waitcnt vmcnt(8)" ::: "memory");
    __builtin_amdgcn_s_barrier();
    asm volatile("" ::: "memory");

    for (int t = 0; t < 14; t += 2) {
        GTILE(0, t,     1, 1, 6, VMW(8));
        GTILE(1, t + 1, 1, 1, 6, VMW(8));
    }
    GTILE(0, 14, 1, 0, 6, VMW(4));
    GTILE(1, 15, 0, 0, 0, (void)0);

    if (MODE == 1) {
        #pragma unroll
        for (int nh = 0; nh < 2; ++nh)
            #pragma unroll
            for (int ni = 0; ni < 2; ++ni) {
                int col = bn + nh * 128 + wn * 32 + ni * 16 + ml;
                float bv = bias[col];
                #pragma unroll
                for (int mh = 0; mh < 2; ++mh)
                    #pragma unroll
                    for (int mi = 0; mi < 4; ++mi)
                        #pragma unroll
                        for (int r = 0; r < 4; ++r) {
                            int row = bm + mh * 128 + wm * 64 + mi * 16 + quad * 4 + r;
                            out[(size_t)row * 1024 + col] = acc[mh][nh][mi][ni][r] + bv;
                        }
            }
        return;
    }

    // ---- MODE 0 epilogue ----
    const int region = bn >> 10;              // 0=q, 1=k, 2=v (block-uniform)
    const int b  = bm >> 10;
    const int n0 = bm & 1023;
    if (region < 2) {
        // stage rope slice for rows n0..n0+255: Rs[rl][p] (64 KiB, reuse SM)
        float2* Rs = (float2*)SM;
        for (int i = tid; i < 8192; i += 512)
            Rs[i] = rope[(size_t)(n0 + (i >> 5)) * 32 + (i & 31)];
        __syncthreads();
        unsigned short* dst = (region == 0) ? qb : kb;
        const float scale = (region == 0) ? 0.125f : 1.f;
        const float sgn = (ml & 1) ? 1.f : -1.f;
        #pragma unroll
        for (int nh = 0; nh < 2; ++nh)
            #pragma unroll
            for (int ni = 0; ni < 2; ++ni) {
                int col = (bn & 1023) + nh * 128 + wn * 32 + ni * 16 + ml;
                int h = col >> 6, d = col & 63, p = d >> 1;
                #pragma unroll
                for (int mh = 0; mh < 2; ++mh)
                    #pragma unroll
                    for (int mi = 0; mi < 4; ++mi)
                        #pragma unroll
                        for (int r = 0; r < 4; ++r) {
                            int rl = mh * 128 + wm * 64 + mi * 16 + quad * 4 + r;
                            float val = acc[mh][nh][mi][ni][r];
                            float partner = __shfl_xor(val, 1);
                            float2 cs = Rs[rl * 32 + p];
                            dst[(((size_t)(b * Hh + h)) * Nseq + n0 + rl) * Dd + d] =
                                f2bf((val * cs.x + sgn * partner * cs.y) * scale);
                        }
            }
    } else {
        // V: transpose 256 cols x 128 rows per pass via LDS -> vt (B,H,D,N)
        short* T = SM;                        // [256][136] shorts = 68 KiB
        const int hb = (bn & 1023) >> 6;      // head base (4 heads per tile)
        #pragma unroll
        for (int mh = 0; mh < 2; ++mh) {
            if (mh) __syncthreads();          // prior pass reads done
            #pragma unroll
            for (int nh = 0; nh < 2; ++nh)
                #pragma unroll
                for (int ni = 0; ni < 2; ++ni) {
                    int c = nh * 128 + wn * 32 + ni * 16 + ml;
                    #pragma unroll
                    for (int mi = 0; mi < 4; ++mi) {
                        uint2 pk;
                        pk.x = pack_bf16(acc[mh][nh][mi][ni][0], acc[mh][nh][mi][ni][1]);
                        pk.y = pack_bf16(acc[mh][nh][mi][ni][2], acc[mh][nh][mi][ni][3]);
                        *(uint2*)&T[c * 136 + wm * 64 + mi * 16 + quad * 4] = pk;
                    }
                }
            __syncthreads();
            for (int i = tid; i < 8192; i += 512) {
                int c = i >> 5, seg = i & 31;
                ushort4 v4 = *(const ushort4*)&T[c * 136 + seg * 4];
                int h = hb + (c >> 6), d = c & 63;
                *(ushort4*)(vtb + (((size_t)(b * Hh + h)) * Dd + d) * Nseq
                            + n0 + mh * 128 + seg * 4) = v4;
            }
        }
    }
}

// ---------------------------------------------------------------------------
// MFMA flash attention (validated): no-max softmax, 128 q-rows/block,
// software-pipelined V(kt)/K(kt+1) staging, Q fragments hoisted to registers.
// ---------------------------------------------------------------------------
__global__ __launch_bounds__(256) void attn_flash_mfma(
    const unsigned short* __restrict__ qb, const unsigned short* __restrict__ kb,
    const unsigned short* __restrict__ vt, unsigned short* __restrict__ ao)
{
    const int bh  = blockIdx.x;   // 0..127
    const int qt  = blockIdx.y;   // 0..7
    const int tid = threadIdx.x;
    const int wave = tid >> 6, lane = tid & 63;
    const int ml = lane & 15, quad = lane >> 4;
    const int lr = lane >> 3;
    const int lc = ((lane & 7) ^ lr) * 8;

    __shared__ short Qs[128][64];  // [q][d] (pre-scaled by 0.125)
    __shared__ short Ks[64][64];   // [key][d]
    __shared__ short Vs[64][64];   // [d][key]
    __shared__ short Ps[4][32][72];// per-wave P [q_local][key]

    const size_t hbase = (size_t)bh * (Nseq * Dd);
    const size_t vbase = (size_t)bh * 64;
    const int q0 = qt * 128;
    const int wq = wave * 32;
    const int wk = wave * 16;

    #pragma unroll
    for (int t = 0; t < 4; ++t)
        async16(qb + hbase + (size_t)(q0 + wq + t * 8 + lr) * 64 + lc, &Qs[wq + t * 8][0]);
    async16(kb + hbase + (size_t)(wk + lr) * 64 + lc,     &Ks[wk][0]);
    async16(kb + hbase + (size_t)(wk + 8 + lr) * 64 + lc, &Ks[wk + 8][0]);
    __syncthreads();

    short8 qfr[2][2];
    #pragma unroll
    for (int ks = 0; ks < 2; ++ks) {
        const int sl = ((ks * 4 + quad) ^ (ml & 7)) * 8;
        qfr[ks][0] = *(const short8*)&Qs[wq + ml][sl];
        qfr[ks][1] = *(const short8*)&Qs[wq + 16 + ml][sl];
    }

    float l0 = 0.f, l1 = 0.f;
    floatx4 o[2][4] = {};

    for (int kt = 0; kt < 16; ++kt) {
        const int k0r = kt * 64;
        async16(vt + (vbase + wk + lr) * Nseq + k0r + lc,     &Vs[wk][0]);
        async16(vt + (vbase + wk + 8 + lr) * Nseq + k0r + lc, &Vs[wk + 8][0]);

        floatx4 st[2][4] = {};
        #pragma unroll
        for (int ks = 0; ks < 2; ++ks) {
            const int sl = ((ks * 4 + quad) ^ (ml & 7)) * 8;
            #pragma unroll
            for (int kbk = 0; kbk < 4; ++kbk) {
                short8 kf = *(const short8*)&Ks[kbk * 16 + ml][sl];
                st[0][kbk] = __builtin_amdgcn_mfma_f32_16x16x32_bf16(kf, qfr[ks][0], st[0][kbk], 0, 0, 0);
                st[1][kbk] = __builtin_amdgcn_mfma_f32_16x16x32_bf16(kf, qfr[ks][1], st[1][kbk], 0, 0, 0);
            }
        }

        #pragma unroll
        for (int qg = 0; qg < 2; ++qg) {
            float lacc = 0.f;
            #pragma unroll
            for (int kbk = 0; kbk < 4; ++kbk) {
                float e0 = __expf(st[qg][kbk][0]);
                float e1 = __expf(st[qg][kbk][1]);
                float e2 = __expf(st[qg][kbk][2]);
                float e3 = __expf(st[qg][kbk][3]);
                lacc += (e0 + e1) + (e2 + e3);
                uint2 pk;
                pk.x = pack_bf16(e0, e1);
                pk.y = pack_bf16(e2, e3);
                *(uint2*)&Ps[wave][qg * 16 + ml][kbk * 16 + quad * 4] = pk;
            }
            if (qg == 0) l0 += lacc; else l1 += lacc;
        }
        __syncthreads();   // V(kt) visible; all waves done with Ks(kt)

        if (kt < 15) {
            const int k1r = k0r + 64;
            async16(kb + hbase + (size_t)(k1r + wk + lr) * 64 + lc,     &Ks[wk][0]);
            async16(kb + hbase + (size_t)(k1r + wk + 8 + lr) * 64 + lc, &Ks[wk + 8][0]);
        }

        #pragma unroll
        for (int ks = 0; ks < 2; ++ks) {
            const int sl = ((ks * 4 + quad) ^ (ml & 7)) * 8;
            short8 pf0 = *(const short8*)&Ps[wave][ml][ks * 32 + quad * 8];
            short8 pf1 = *(const short8*)&Ps[wave][16 + ml][ks * 32 + quad * 8];
            #pragma unroll
            for (int nt = 0; nt < 4; ++nt) {
                short8 vf = *(const short8*)&Vs[nt * 16 + ml][sl];
                o[0][nt] = __builtin_amdgcn_mfma_f32_16x16x32_bf16(pf0, vf, o[0][nt], 0, 0, 0);
                o[1][nt] = __builtin_amdgcn_mfma_f32_16x16x32_bf16(pf1, vf, o[1][nt], 0, 0, 0);
            }
        }
        if (kt < 15)
            __syncthreads();
    }

    l0 += __shfl_xor(l0, 16);
    l0 += __shfl_xor(l0, 32);
    l1 += __shfl_xor(l1, 16);
    l1 += __shfl_xor(l1, 32);

    const int b = bh >> 4, h = bh & 15;
    #pragma unroll
    for (int qg = 0; qg < 2; ++qg) {
        float lsrc = (qg == 0) ? l0 : l1;
        #pragma unroll
        for (int r = 0; r < 4; ++r) {
            float lq = __shfl(lsrc, quad * 4 + r);
            float inv = 1.f / lq;
            int q = q0 + wq + qg * 16 + quad * 4 + r;
            size_t rowbase = ((size_t)(b * Nseq + q)) * Cdim + h * Dd;
            #pragma unroll
            for (int nt = 0; nt < 4; ++nt)
                ao[rowbase + nt * 16 + ml] = f2bf(o[qg][nt][r] * inv);
        }
    }
}

extern "C" void kernel_launch(void* const* d_in, const int* in_sizes, int n_in,
                              void* d_out, int out_size, void* d_ws, size_t ws_size,
                              hipStream_t stream) {
    const float* x      = (const float*)d_in[0];
    const float* w_qkv  = (const float*)d_in[1];
    const float* w_proj = (const float*)d_in[2];
    const float* b_proj = (const float*)d_in[3];
    float* out = (float*)d_out;

    const size_t M8 = (size_t)8 * 1024 * 1024;
    unsigned short* qb     = (unsigned short*)d_ws;
    unsigned short* kb     = qb + M8;
    unsigned short* vt     = kb + M8;                  // (B,H,D,N)
    unsigned short* xb     = vt + M8;                  // reused as aob
    unsigned short* wqkvt  = xb + M8;                  // 3072 x 1024
    unsigned short* wprojt = wqkvt + 3 * 1024 * 1024;  // 1024 x 1024
    float2*         rope   = (float2*)(wprojt + 1024 * 1024);  // 1024 x 32
    unsigned short* aob    = xb;   // alias: xb dead after gemm0

    prep<<<9344, 256, 0, stream>>>(x, w_qkv, w_proj, xb, wqkvt, wprojt, rope);

    gemm256<0><<<dim3(12, 32), 512, 0, stream>>>(xb, wqkvt, nullptr, rope,
                                                 qb, kb, vt, nullptr);

    attn_flash_mfma<<<dim3(128, 8), 256, 0, stream>>>(qb, kb, vt, aob);

    gemm256<1><<<dim3(4, 32), 512, 0, stream>>>(aob, wprojt, b_proj, nullptr,
                                                nullptr, nullptr, nullptr, out);
}

// Round 2
// 231.979 us; speedup vs baseline: 1.1473x; 1.1473x over previous
//
#include <hip/hip_runtime.h>
#include <hip/hip_bf16.h>
#include <math.h>

#define Bsz  8
#define Nseq 1024
#define Cdim 1024
#define Hh   16
#define Dd   64

typedef short short8 __attribute__((ext_vector_type(8)));
typedef float floatx4 __attribute__((ext_vector_type(4)));

__device__ __forceinline__ unsigned short f2bf(float f) {
    __hip_bfloat16 h = __float2bfloat16(f);
    return __builtin_bit_cast(unsigned short, h);
}

// async 16B global -> LDS. LDS dest is wave-uniform base + lane*16 (HW rule).
__device__ __forceinline__ void async16(const void* g, void* l) {
    __builtin_amdgcn_global_load_lds(
        (const __attribute__((address_space(1))) unsigned int*)g,
        (__attribute__((address_space(3))) unsigned int*)l, 16, 0, 0);
}

// pack two fp32 -> two bf16 (round-half-up) in one dword
__device__ __forceinline__ unsigned pack_bf16(float lo, float hi) {
    unsigned ulo = __float_as_uint(lo) + 0x8000u;
    unsigned uhi = __float_as_uint(hi) + 0x8000u;
    return __builtin_amdgcn_perm(uhi, ulo, 0x07060302);  // [ulo>>16, uhi>>16]
}

// ---------------------------------------------------------------------------
// PREP (fused): [0,8192) convert X fp32->bf16; [8192,8960) transpose w_qkv;
// [8960,9216) transpose w_proj; [9216,9344) RoPE table.
// ---------------------------------------------------------------------------
__global__ __launch_bounds__(256) void prep(
    const float* __restrict__ x, const float* __restrict__ w_qkv,
    const float* __restrict__ w_proj,
    unsigned short* __restrict__ xb, unsigned short* __restrict__ wqkvt,
    unsigned short* __restrict__ wprojt, float2* __restrict__ rope)
{
    __shared__ float T[64][65];
    const int blk = blockIdx.x;
    const int tid = threadIdx.x;

    if (blk < 8192) {
        int i = blk * 256 + tid;
        float4 v = ((const float4*)x)[i];
        ushort4 u;
        u.x = f2bf(v.x); u.y = f2bf(v.y); u.z = f2bf(v.z); u.w = f2bf(v.w);
        ((ushort4*)xb)[i] = u;
        return;
    }
    if (blk < 9216) {
        const float* in;
        unsigned short* out;
        int R = 1024, Ccols, c0, r0;
        if (blk < 8960) {
            int b2 = blk - 8192;
            in = w_qkv; out = wqkvt; Ccols = 3072;
            c0 = (b2 % 48) * 64; r0 = (b2 / 48) * 64;
        } else {
            int b2 = blk - 8960;
            in = w_proj; out = wprojt; Ccols = 1024;
            c0 = (b2 % 16) * 64; r0 = (b2 / 16) * 64;
        }
        for (int i = tid; i < 4096; i += 256) {
            int r = i >> 6, c = i & 63;
            T[r][c] = in[(size_t)(r0 + r) * Ccols + c0 + c];
        }
        __syncthreads();
        for (int i = tid; i < 4096; i += 256) {
            int rr = i >> 6, cc = i & 63;
            out[(size_t)(c0 + rr) * R + r0 + cc] = f2bf(T[cc][rr]);
        }
        return;
    }
    {
        int i = (blk - 9216) * 256 + tid;     // 0..32767
        int n = i >> 5, p = i & 31;
        float omega = __expf(-(float)p * 0.2878231366242557f);
        float sv, cv;
        sincosf((float)n * omega, &sv, &cv);
        rope[i] = make_float2(cv, sv);
    }
}

// ---------------------------------------------------------------------------
// bf16 MFMA GEMM, BK=64 (16 K-iters, 32 KB LDS, attention-style XOR swizzle:
// rows are 128B = 8 chunks; chunk c of row r lives at slot c^(r&7) —
// 8-lane phases hit 8 distinct slots -> conflict-free).
// XCD-aware block swizzle (T1): each XCD gets a contiguous chunk of the
// by-major linear id -> A-panels (2 MB per XCD chunk) become L2-resident,
// shortening the per-K-step staging-drain latency.
// MODE 0: N=3072; epilogue applies RoPE from an LDS-staged table slice and
//         scatters q,k -> (B,H,N,D); v is LDS-transposed -> vt (B,H,D,N).
// MODE 1: N=1024, +bias -> fp32 out.
// ---------------------------------------------------------------------------
template <int MODE>
__global__ __launch_bounds__(256) void gemm_bf16(
    const unsigned short* __restrict__ A, const unsigned short* __restrict__ Bt,
    const float* __restrict__ bias, const float2* __restrict__ rope,
    unsigned short* __restrict__ qb, unsigned short* __restrict__ kb,
    unsigned short* __restrict__ vtb, float* __restrict__ out)
{
    const int K = 1024;
    __shared__ short SM[2][128][64];   // [0]=As, [1]=Bs; reused by epilogue
    const int tid  = threadIdx.x;
    const int wave = tid >> 6, lane = tid & 63;
    const int ml = lane & 15, quad = lane >> 4;
    const int wm = wave >> 1, wn = wave & 1;

    // XCD-aware bijective remap (nwg % 8 == 0 for both modes)
    int lin = blockIdx.y * gridDim.x + blockIdx.x;
    const int nwg = gridDim.x * gridDim.y;
    lin = (lin & 7) * (nwg >> 3) + (lin >> 3);
    const int bx = lin % gridDim.x, by = lin / gridDim.x;
    const int bm = by * 128, bn = bx * 128;

    const int lr     = lane >> 3;                 // row within 8-row group
    const int lchunk = ((lane & 7) ^ lr) * 8;     // swizzled source chunk (shorts)

    floatx4 acc[4][4] = {};

    for (int k0 = 0; k0 < K; k0 += 64) {
        #pragma unroll
        for (int t = 0; t < 4; ++t) {
            int r8  = (wave * 4 + t) * 8;
            int row = r8 + lr;
            async16(A  + (size_t)(bm + row) * K + k0 + lchunk, &SM[0][r8][0]);
            async16(Bt + (size_t)(bn + row) * K + k0 + lchunk, &SM[1][r8][0]);
        }
        __syncthreads();

        #pragma unroll
        for (int ks = 0; ks < 2; ++ks) {
            const int sl = ((ks * 4 + quad) ^ (ml & 7)) * 8;
            short8 araw[4], braw[4];
            #pragma unroll
            for (int mi = 0; mi < 4; ++mi)
                araw[mi] = *(const short8*)&SM[0][wm * 64 + mi * 16 + ml][sl];
            #pragma unroll
            for (int ni = 0; ni < 4; ++ni)
                braw[ni] = *(const short8*)&SM[1][wn * 64 + ni * 16 + ml][sl];
            #pragma unroll
            for (int mi = 0; mi < 4; ++mi)
                #pragma unroll
                for (int ni = 0; ni < 4; ++ni)
                    acc[mi][ni] = __builtin_amdgcn_mfma_f32_16x16x32_bf16(
                        araw[mi], braw[ni], acc[mi][ni], 0, 0, 0);
        }
        __syncthreads();   // frag reads done before next stage / epilogue reuse
    }

    if (MODE == 0) {
        const int region = bn >> 10;              // 0=q, 1=k, 2=v (block-uniform)
        const int b = bm >> 10;
        if (region < 2) {
            // stage rope slice for rows bm..bm+127: Rs[rl][p], 4096 float2 = 32 KB
            float2* Rs = (float2*)&SM[0][0][0];
            #pragma unroll
            for (int t = 0; t < 16; ++t) {
                int idx = t * 256 + tid;
                Rs[idx] = rope[(size_t)((bm + (idx >> 5)) & 1023) * 32 + (idx & 31)];
            }
            __syncthreads();
            unsigned short* dst = (region == 0) ? qb : kb;
            const float scale = (region == 0) ? 0.125f : 1.f;
            const float sgn = (ml & 1) ? 1.f : -1.f;
            #pragma unroll
            for (int ni = 0; ni < 4; ++ni) {
                int col = bn + wn * 64 + ni * 16 + ml;
                int jj = col & 1023;
                int h = jj >> 6, d = jj & 63;
                int p = d >> 1;
                #pragma unroll
                for (int mi = 0; mi < 4; ++mi)
                    #pragma unroll
                    for (int r = 0; r < 4; ++r) {
                        int rl = wm * 64 + mi * 16 + quad * 4 + r;
                        int n  = (bm + rl) & 1023;
                        float val = acc[mi][ni][r];
                        float partner = __shfl_xor(val, 1);
                        float2 cs = Rs[rl * 32 + p];
                        dst[(((size_t)(b * Hh + h)) * Nseq + n) * Dd + d] =
                            f2bf((val * cs.x + sgn * partner * cs.y) * scale);
                    }
            }
        } else {
            // V: transpose via LDS (two 64-col halves), store (B,H,D,N) coalesced
            short* T = &SM[0][0][0];              // [64][132] = 16.9 KB
            const int n0 = bm & 1023;
            #pragma unroll
            for (int hw = 0; hw < 2; ++hw) {
                if (hw) __syncthreads();          // prior half's reads done
                if (wn == hw) {
                    #pragma unroll
                    for (int ni = 0; ni < 4; ++ni) {
                        int dcol = ni * 16 + ml;
                        #pragma unroll
                        for (int mi = 0; mi < 4; ++mi)
                            #pragma unroll
                            for (int r = 0; r < 4; ++r) {
                                int rl = wm * 64 + mi * 16 + quad * 4 + r;
                                T[dcol * 132 + rl] = (short)f2bf(acc[mi][ni][r]);
                            }
                    }
                }
                __syncthreads();
                int h = ((bn & 1023) >> 6) + hw;
                #pragma unroll
                for (int t = 0; t < 8; ++t) {
                    int idx4 = t * 256 + tid;     // 0..2047 ushort4 units
                    int d = idx4 >> 5, seg = idx4 & 31;
                    ushort4 v4 = *(const ushort4*)&T[d * 132 + seg * 4];
                    *(ushort4*)(vtb + (((size_t)(b * Hh + h)) * Dd + d) * Nseq
                                + n0 + seg * 4) = v4;
                }
            }
        }
    } else {
        #pragma unroll
        for (int ni = 0; ni < 4; ++ni) {
            int col = bn + wn * 64 + ni * 16 + ml;
            float bv = bias[col];
            #pragma unroll
            for (int mi = 0; mi < 4; ++mi)
                #pragma unroll
                for (int r = 0; r < 4; ++r) {
                    int row = bm + wm * 64 + mi * 16 + quad * 4 + r;
                    out[(size_t)row * 1024 + col] = acc[mi][ni][r] + bv;
                }
        }
    }
}

// ---------------------------------------------------------------------------
// MFMA flash attention: no-max softmax, 128 q-rows/block, software-pipelined
// V(kt)/K(kt+1) staging, Q fragments hoisted to registers.
// Round-2: LDS union (Qs is prologue-only -> overlay with Vs+Ps): 50.4 KB ->
// 34 KB => 4 blocks/CU (launch_bounds(256,4)); s_setprio(1) around MFMA
// clusters (T5, measured +4-7% on attn).
// ---------------------------------------------------------------------------
__global__ __launch_bounds__(256, 4) void attn_flash_mfma(
    const unsigned short* __restrict__ qb, const unsigned short* __restrict__ kb,
    const unsigned short* __restrict__ vt, unsigned short* __restrict__ ao)
{
    const int bh  = blockIdx.x;   // 0..127
    const int qt  = blockIdx.y;   // 0..7
    const int tid = threadIdx.x;
    const int wave = tid >> 6, lane = tid & 63;
    const int ml = lane & 15, quad = lane >> 4;
    const int lr = lane >> 3;
    const int lc = ((lane & 7) ^ lr) * 8;

    // 34 KB total: Ks[64][64] | U = union{ Qs[128][64] (prologue only),
    //                                      Vs[64][64] + Ps[4][32][72] }
    __shared__ __attribute__((aligned(16))) short SMEM[17408];
    short (*Ks)[64] = (short(*)[64])SMEM;                 // 4096 shorts
    short* U = SMEM + 4096;
    short (*Qs)[64] = (short(*)[64])U;                    // 8192 shorts
    short (*Vs)[64] = (short(*)[64])U;                    // 4096 shorts
    short (*Ps)[32][72] = (short(*)[32][72])(U + 4096);   // 9216 shorts

    const size_t hbase = (size_t)bh * (Nseq * Dd);
    const size_t vbase = (size_t)bh * 64;
    const int q0 = qt * 128;
    const int wq = wave * 32;
    const int wk = wave * 16;

    #pragma unroll
    for (int t = 0; t < 4; ++t)
        async16(qb + hbase + (size_t)(q0 + wq + t * 8 + lr) * 64 + lc, &Qs[wq + t * 8][0]);
    async16(kb + hbase + (size_t)(wk + lr) * 64 + lc,     &Ks[wk][0]);
    async16(kb + hbase + (size_t)(wk + 8 + lr) * 64 + lc, &Ks[wk + 8][0]);
    __syncthreads();

    short8 qfr[2][2];
    #pragma unroll
    for (int ks = 0; ks < 2; ++ks) {
        const int sl = ((ks * 4 + quad) ^ (ml & 7)) * 8;
        qfr[ks][0] = *(const short8*)&Qs[wq + ml][sl];
        qfr[ks][1] = *(const short8*)&Qs[wq + 16 + ml][sl];
    }
    __syncthreads();   // qfr reads complete in all waves: U reusable (Vs/Ps)

    float l0 = 0.f, l1 = 0.f;
    floatx4 o[2][4] = {};

    for (int kt = 0; kt < 16; ++kt) {
        const int k0r = kt * 64;
        async16(vt + (vbase + wk + lr) * Nseq + k0r + lc,     &Vs[wk][0]);
        async16(vt + (vbase + wk + 8 + lr) * Nseq + k0r + lc, &Vs[wk + 8][0]);

        floatx4 st[2][4] = {};
        __builtin_amdgcn_s_setprio(1);
        #pragma unroll
        for (int ks = 0; ks < 2; ++ks) {
            const int sl = ((ks * 4 + quad) ^ (ml & 7)) * 8;
            #pragma unroll
            for (int kbk = 0; kbk < 4; ++kbk) {
                short8 kf = *(const short8*)&Ks[kbk * 16 + ml][sl];
                st[0][kbk] = __builtin_amdgcn_mfma_f32_16x16x32_bf16(kf, qfr[ks][0], st[0][kbk], 0, 0, 0);
                st[1][kbk] = __builtin_amdgcn_mfma_f32_16x16x32_bf16(kf, qfr[ks][1], st[1][kbk], 0, 0, 0);
            }
        }
        __builtin_amdgcn_s_setprio(0);

        #pragma unroll
        for (int qg = 0; qg < 2; ++qg) {
            float lacc = 0.f;
            #pragma unroll
            for (int kbk = 0; kbk < 4; ++kbk) {
                float e0 = __expf(st[qg][kbk][0]);
                float e1 = __expf(st[qg][kbk][1]);
                float e2 = __expf(st[qg][kbk][2]);
                float e3 = __expf(st[qg][kbk][3]);
                lacc += (e0 + e1) + (e2 + e3);
                uint2 pk;
                pk.x = pack_bf16(e0, e1);
                pk.y = pack_bf16(e2, e3);
                *(uint2*)&Ps[wave][qg * 16 + ml][kbk * 16 + quad * 4] = pk;
            }
            if (qg == 0) l0 += lacc; else l1 += lacc;
        }
        __syncthreads();   // V(kt) visible; all waves done with Ks(kt)

        if (kt < 15) {
            const int k1r = k0r + 64;
            async16(kb + hbase + (size_t)(k1r + wk + lr) * 64 + lc,     &Ks[wk][0]);
            async16(kb + hbase + (size_t)(k1r + wk + 8 + lr) * 64 + lc, &Ks[wk + 8][0]);
        }

        __builtin_amdgcn_s_setprio(1);
        #pragma unroll
        for (int ks = 0; ks < 2; ++ks) {
            const int sl = ((ks * 4 + quad) ^ (ml & 7)) * 8;
            short8 pf0 = *(const short8*)&Ps[wave][ml][ks * 32 + quad * 8];
            short8 pf1 = *(const short8*)&Ps[wave][16 + ml][ks * 32 + quad * 8];
            #pragma unroll
            for (int nt = 0; nt < 4; ++nt) {
                short8 vf = *(const short8*)&Vs[nt * 16 + ml][sl];
                o[0][nt] = __builtin_amdgcn_mfma_f32_16x16x32_bf16(pf0, vf, o[0][nt], 0, 0, 0);
                o[1][nt] = __builtin_amdgcn_mfma_f32_16x16x32_bf16(pf1, vf, o[1][nt], 0, 0, 0);
            }
        }
        __builtin_amdgcn_s_setprio(0);
        if (kt < 15)
            __syncthreads();
    }

    l0 += __shfl_xor(l0, 16);
    l0 += __shfl_xor(l0, 32);
    l1 += __shfl_xor(l1, 16);
    l1 += __shfl_xor(l1, 32);

    const int b = bh >> 4, h = bh & 15;
    #pragma unroll
    for (int qg = 0; qg < 2; ++qg) {
        float lsrc = (qg == 0) ? l0 : l1;
        #pragma unroll
        for (int r = 0; r < 4; ++r) {
            float lq = __shfl(lsrc, quad * 4 + r);
            float inv = 1.f / lq;
            int q = q0 + wq + qg * 16 + quad * 4 + r;
            size_t rowbase = ((size_t)(b * Nseq + q)) * Cdim + h * Dd;
            #pragma unroll
            for (int nt = 0; nt < 4; ++nt)
                ao[rowbase + nt * 16 + ml] = f2bf(o[qg][nt][r] * inv);
        }
    }
}

extern "C" void kernel_launch(void* const* d_in, const int* in_sizes, int n_in,
                              void* d_out, int out_size, void* d_ws, size_t ws_size,
                              hipStream_t stream) {
    const float* x      = (const float*)d_in[0];
    const float* w_qkv  = (const float*)d_in[1];
    const float* w_proj = (const float*)d_in[2];
    const float* b_proj = (const float*)d_in[3];
    float* out = (float*)d_out;

    const size_t M8 = (size_t)8 * 1024 * 1024;
    unsigned short* qb     = (unsigned short*)d_ws;
    unsigned short* kb     = qb + M8;
    unsigned short* vt     = kb + M8;                  // (B,H,D,N)
    unsigned short* xb     = vt + M8;                  // reused as aob
    unsigned short* wqkvt  = xb + M8;                  // 3072 x 1024
    unsigned short* wprojt = wqkvt + 3 * 1024 * 1024;  // 1024 x 1024
    float2*         rope   = (float2*)(wprojt + 1024 * 1024);  // 1024 x 32
    unsigned short* aob    = xb;   // alias: xb dead after gemm0

    prep<<<9344, 256, 0, stream>>>(x, w_qkv, w_proj, xb, wqkvt, wprojt, rope);

    gemm_bf16<0><<<dim3(24, 64), 256, 0, stream>>>(xb, wqkvt, nullptr, rope,
                                                   qb, kb, vt, nullptr);

    attn_flash_mfma<<<dim3(128, 8), 256, 0, stream>>>(qb, kb, vt, aob);

    gemm_bf16<1><<<dim3(8, 64), 256, 0, stream>>>(aob, wprojt, b_proj, nullptr,
                                                  nullptr, nullptr, nullptr, out);
}